// Round 1
// baseline (596.457 us; speedup 1.0000x reference)
//
#include <hip/hip_runtime.h>

// BatchedHGNNLayer: out = [Dv^-1/2 H De^-1 H^T Dv^-1/2 x] W^T + b
// B=8, N=4096, E=2048, C=128. Strategy:
//   K1: read H fp32 once -> Dv (row sums), De (col sums, atomics),
//       H_bf16 [n][e] (for GEMM2) and HT_bf16 [e][n] (for GEMM1) via LDS transpose
//   K2: xsT[c][n] = bf16(x[n][c] * rsqrt(Dv+eps))   (scale + transpose)
//   K3: GEMM1 (split-K=4, atomic f32): out2[e][c] += sum_n HT[e][n]*xsT[c][n]
//   K3b: out2T[c][e] = bf16(out2[e][c] / (De+eps))  (scale + transpose)
//   K4: GEMM2 (split-K=2, atomic f32 into d_out): out3[n][c] += sum_e H[n][e]*out2T[c][e]
//   K5: in-place final: out[n][co] = sum_ci bf16(out3[n][ci]*rsqrt(Dv))*bf16(W[co][ci]) + b[co]
// All MFMA accumulation fp32; only H/xs/out2T/W are rounded to bf16 (error ~1e-4 abs,
// threshold 1.38e-3).
// Workspace: 2*134MB (H copies) + 8MB + 8MB + 4MB + 0.2MB ~= 277 MB required.

#define EPS 1e-6f
constexpr int B_ = 8, N_ = 4096, E_ = 2048, C_ = 128;

typedef __bf16 bf16x8 __attribute__((ext_vector_type(8)));
typedef float f32x4 __attribute__((ext_vector_type(4)));

__device__ __forceinline__ unsigned int f2bf_pack(float lo, float hi) {
  // RNE fp32->bf16 for both, pack lo into low 16 bits
  unsigned int ul = __float_as_uint(lo), uh = __float_as_uint(hi);
  ul = (ul + 0x7fffu + ((ul >> 16) & 1u)) >> 16;
  uh = (uh + 0x7fffu + ((uh >> 16) & 1u)) & 0xffff0000u;
  return uh | ul;
}

__device__ __forceinline__ void gl2lds16(const void* g, void* l) {
  // async global -> LDS, 16B per lane; LDS dest is wave-uniform base + lane*16
  __builtin_amdgcn_global_load_lds(
      (const __attribute__((address_space(1))) void*)g,
      (__attribute__((address_space(3))) void*)l, 16, 0, 0);
}

// ---------------------------------------------------------------------------
// K1: degrees + dual bf16 copies of H.
// grid (N/128, E/1024, B), 256 threads. Block: 128 n-rows x 1024 e in 16 chunks of 64 e.
__global__ __launch_bounds__(256) void k1_prep(
    const float* __restrict__ H, unsigned short* __restrict__ Hbf,
    unsigned short* __restrict__ HT, float* __restrict__ Dv, float* __restrict__ De) {
  __shared__ float T[64][129];  // transposed chunk [e][n], pad->2-way (free) write conflicts
  const int t = threadIdx.x;
  const int b = blockIdx.z;
  const int n0 = blockIdx.x * 128;
  const int ebase = blockIdx.y * 1024;
  const int nloc = t >> 1, eh = t & 1;   // load/store mapping: 2 thr per n-row
  const int erow = t >> 2, nq = t & 3;   // phase2 mapping: 4 thr per e-row
  const float* Hrow = H + ((size_t)b * N_ + n0 + nloc) * E_;
  unsigned short* HbfRow = Hbf + ((size_t)b * N_ + n0 + nloc) * E_;
  float rowsum = 0.f;
  for (int ch = 0; ch < 16; ++ch) {
    const int e0 = ebase + ch * 64;
    const int eoff = e0 + eh * 32;
    f32x4 v[8];
    const f32x4* src = (const f32x4*)(Hrow + eoff);
#pragma unroll
    for (int i = 0; i < 8; ++i) v[i] = src[i];
    // row-sum partial + write H_bf16 (same layout, coalesced)
    unsigned int pk[16];
#pragma unroll
    for (int i = 0; i < 8; ++i) {
      rowsum += v[i][0] + v[i][1] + v[i][2] + v[i][3];
      pk[2 * i] = f2bf_pack(v[i][0], v[i][1]);
      pk[2 * i + 1] = f2bf_pack(v[i][2], v[i][3]);
    }
    uint4* dst = (uint4*)(HbfRow + eoff);
#pragma unroll
    for (int i = 0; i < 4; ++i)
      dst[i] = make_uint4(pk[4 * i], pk[4 * i + 1], pk[4 * i + 2], pk[4 * i + 3]);
    __syncthreads();  // previous chunk's readers done with T
#pragma unroll
    for (int i = 0; i < 8; ++i) {
      const int el = eh * 32 + 4 * i;
      T[el + 0][nloc] = v[i][0];
      T[el + 1][nloc] = v[i][1];
      T[el + 2][nloc] = v[i][2];
      T[el + 3][nloc] = v[i][3];
    }
    __syncthreads();
    // phase2: column (De) partials + HT write, from transposed tile
    float csum = 0.f;
    unsigned int hp[16];
#pragma unroll
    for (int i = 0; i < 16; ++i) {
      const float a0 = T[erow][nq * 32 + 2 * i];
      const float a1 = T[erow][nq * 32 + 2 * i + 1];
      csum += a0 + a1;
      hp[i] = f2bf_pack(a0, a1);
    }
    uint4* hdst = (uint4*)(HT + ((size_t)b * E_ + e0 + erow) * N_ + n0 + nq * 32);
#pragma unroll
    for (int i = 0; i < 4; ++i)
      hdst[i] = make_uint4(hp[4 * i], hp[4 * i + 1], hp[4 * i + 2], hp[4 * i + 3]);
    csum += __shfl_down(csum, 1);
    csum += __shfl_down(csum, 2);
    if ((t & 3) == 0) atomicAdd(&De[b * E_ + e0 + erow], csum);
  }
  rowsum += __shfl_down(rowsum, 1);
  if (eh == 0) atomicAdd(&Dv[b * N_ + n0 + nloc], rowsum);
}

// ---------------------------------------------------------------------------
// K2/K3b: outT[c][r] = bf16(in[r][c] * scale(deg[r])).  MODE 0: rsqrt, 1: recip.
// grid (R/128, B), 256 threads. 128r x 128c tile, bf16x2 pairs in LDS.
template <int MODE>
__global__ __launch_bounds__(256) void scale_transpose(
    const float* __restrict__ in, const float* __restrict__ deg,
    unsigned short* __restrict__ outT, int R) {
  __shared__ unsigned int T[128][66];  // [c][row-pair]
  const int t = threadIdx.x;
  in += (size_t)blockIdx.y * R * 128;
  outT += (size_t)blockIdx.y * 128 * R;
  deg += (size_t)blockIdx.y * R;
  const int r0 = blockIdx.x * 128;
  const int q = t >> 2, cq = t & 3;  // rows 2q,2q+1; interleaved 4-col chunks
  const float* row0 = in + (size_t)(r0 + 2 * q) * 128;
  const float* row1 = row0 + 128;
  const float d0 = deg[r0 + 2 * q] + EPS, d1 = deg[r0 + 2 * q + 1] + EPS;
  float s0, s1;
  if (MODE == 0) { s0 = 1.f / sqrtf(d0); s1 = 1.f / sqrtf(d1); }
  else { s0 = 1.f / d0; s1 = 1.f / d1; }
#pragma unroll
  for (int i = 0; i < 8; ++i) {
    const int c = 16 * i + 4 * cq;
    const f32x4 a = *(const f32x4*)(row0 + c);
    const f32x4 b2 = *(const f32x4*)(row1 + c);
#pragma unroll
    for (int j = 0; j < 4; ++j) T[c + j][q] = f2bf_pack(a[j] * s0, b2[j] * s1);
  }
  __syncthreads();
  const int crow = t >> 1, h = t & 1;
  unsigned int u[32];
#pragma unroll
  for (int i = 0; i < 32; ++i) u[i] = T[crow][h * 32 + i];
  uint4* dst = (uint4*)(outT + (size_t)crow * R + r0 + 64 * h);
#pragma unroll
  for (int i = 0; i < 8; ++i)
    dst[i] = make_uint4(u[4 * i], u[4 * i + 1], u[4 * i + 2], u[4 * i + 3]);
}

// ---------------------------------------------------------------------------
// m97-style bf16 gemm_bt with split-K + atomic f32 epilogue.
// A: [batch][M][Kfull] k-fast; Bt: [batch][128][Kfull] k-fast; C: [batch][M][128] f32.
// grid (M/128, nsplit, batch), 256 threads (4 waves, each 64x64 of the 128x128 tile).
__global__ __launch_bounds__(256) void gemm_bt_splitk(
    const unsigned short* __restrict__ A, const unsigned short* __restrict__ Bt,
    float* __restrict__ Cacc, int M, int Kfull, int Kper) {
  __shared__ unsigned short Als[128 * 32];
  __shared__ unsigned short Bls[128 * 32];
  const int t = threadIdx.x;
  const int w = t >> 6, l = t & 63;
  const int mt = blockIdx.x, sk = blockIdx.y, b = blockIdx.z;
  const unsigned short* Ab = A + ((size_t)b * M + mt * 128) * Kfull + (size_t)sk * Kper;
  const unsigned short* Btb = Bt + (size_t)b * 128 * Kfull + (size_t)sk * Kper;
  const int srow = l >> 2, scol = (l & 3) * 8;  // staging: 4 lanes x 16B per row
  const unsigned short* ga0 = Ab + (size_t)(w * 32 + srow) * Kfull + scol;
  const unsigned short* ga1 = ga0 + (size_t)16 * Kfull;
  const unsigned short* gb0 = Btb + (size_t)(w * 32 + srow) * Kfull + scol;
  const unsigned short* gb1 = gb0 + (size_t)16 * Kfull;
  unsigned short* const la0 = Als + (w * 32) * 32;       // wave-uniform LDS bases
  unsigned short* const la1 = Als + (w * 32 + 16) * 32;
  unsigned short* const lb0 = Bls + (w * 32) * 32;
  unsigned short* const lb1 = Bls + (w * 32 + 16) * 32;
  const int mrow = (w & 1) * 64, ncol = (w >> 1) * 64;
  const int fr = l & 15, fq = l >> 4;
  f32x4 acc[4][4];
#pragma unroll
  for (int i = 0; i < 4; ++i)
#pragma unroll
    for (int j = 0; j < 4; ++j) acc[i][j] = (f32x4){0.f, 0.f, 0.f, 0.f};
  const int nsteps = Kper / 32;
  for (int kt = 0; kt < nsteps; ++kt) {
    __syncthreads();  // protect LDS from previous iteration's readers
    gl2lds16(ga0, la0);
    gl2lds16(ga1, la1);
    gl2lds16(gb0, lb0);
    gl2lds16(gb1, lb1);
    ga0 += 32; ga1 += 32; gb0 += 32; gb1 += 32;
    __syncthreads();  // compiler drains vmcnt before barrier
    bf16x8 af[4], bfr[4];
#pragma unroll
    for (int i = 0; i < 4; ++i) {
      af[i] = *(const bf16x8*)(Als + (mrow + i * 16 + fr) * 32 + fq * 8);
      bfr[i] = *(const bf16x8*)(Bls + (ncol + i * 16 + fr) * 32 + fq * 8);
    }
#pragma unroll
    for (int i = 0; i < 4; ++i)
#pragma unroll
      for (int j = 0; j < 4; ++j)
        acc[i][j] = __builtin_amdgcn_mfma_f32_16x16x32_bf16(af[i], bfr[j], acc[i][j], 0, 0, 0);
  }
  float* Cb = Cacc + ((size_t)b * M + mt * 128) * 128;
#pragma unroll
  for (int i = 0; i < 4; ++i)
#pragma unroll
    for (int j = 0; j < 4; ++j)
#pragma unroll
      for (int r = 0; r < 4; ++r) {
        const int row = mrow + i * 16 + fq * 4 + r;  // C/D: col=lane&15, row=quad*4+reg
        const int col = ncol + j * 16 + fr;
        atomicAdd(Cb + (size_t)row * 128 + col, acc[i][j][r]);
      }
}

// ---------------------------------------------------------------------------
// K5: in-place final linear. io holds out3 accum (f32); out = bf16(io*rs[n]) @ W^T + b.
// grid (B*N/128), 256 threads. W [co][ci] is already B^T layout.
__global__ __launch_bounds__(256) void k5_linear(
    float* __restrict__ io, const float* __restrict__ W,
    const float* __restrict__ bias, const float* __restrict__ Dv) {
  __shared__ unsigned short Als[128 * 136];  // [n][ci], padded
  __shared__ unsigned short Wls[128 * 136];  // [co][ci]
  const int t = threadIdx.x;
  const size_t r0 = (size_t)blockIdx.x * 128;
  {
    const int row = t >> 1, h = t & 1;
    const float* src = io + (r0 + row) * 128 + h * 64;
    const float sc = 1.f / sqrtf(Dv[r0 + row] + EPS);
    unsigned short* ld = Als + row * 136 + h * 64;
    const float* wsrc = W + row * 128 + h * 64;
    unsigned short* lw = Wls + row * 136 + h * 64;
#pragma unroll
    for (int i = 0; i < 16; ++i) {
      const f32x4 a = *(const f32x4*)(src + 4 * i);
      uint2 p;
      p.x = f2bf_pack(a[0] * sc, a[1] * sc);
      p.y = f2bf_pack(a[2] * sc, a[3] * sc);
      *(uint2*)(ld + 4 * i) = p;
      const f32x4 ww = *(const f32x4*)(wsrc + 4 * i);
      uint2 pw;
      pw.x = f2bf_pack(ww[0], ww[1]);
      pw.y = f2bf_pack(ww[2], ww[3]);
      *(uint2*)(lw + 4 * i) = pw;
    }
  }
  __syncthreads();
  const int w = t >> 6, l = t & 63;
  const int mrow = (w & 1) * 64, ncol = (w >> 1) * 64;
  const int fr = l & 15, fq = l >> 4;
  f32x4 acc[4][4];
#pragma unroll
  for (int i = 0; i < 4; ++i)
#pragma unroll
    for (int j = 0; j < 4; ++j) acc[i][j] = (f32x4){0.f, 0.f, 0.f, 0.f};
#pragma unroll
  for (int s = 0; s < 4; ++s) {
    bf16x8 af[4], bfr[4];
#pragma unroll
    for (int i = 0; i < 4; ++i) {
      af[i] = *(const bf16x8*)(Als + (mrow + i * 16 + fr) * 136 + s * 32 + fq * 8);
      bfr[i] = *(const bf16x8*)(Wls + (ncol + i * 16 + fr) * 136 + s * 32 + fq * 8);
    }
#pragma unroll
    for (int i = 0; i < 4; ++i)
#pragma unroll
      for (int j = 0; j < 4; ++j)
        acc[i][j] = __builtin_amdgcn_mfma_f32_16x16x32_bf16(af[i], bfr[j], acc[i][j], 0, 0, 0);
  }
#pragma unroll
  for (int i = 0; i < 4; ++i)
#pragma unroll
    for (int j = 0; j < 4; ++j)
#pragma unroll
      for (int r = 0; r < 4; ++r) {
        const int row = mrow + i * 16 + fq * 4 + r;
        const int col = ncol + j * 16 + fr;
        io[(r0 + row) * 128 + col] = acc[i][j][r] + bias[col];
      }
}

// ---------------------------------------------------------------------------
extern "C" void kernel_launch(void* const* d_in, const int* in_sizes, int n_in,
                              void* d_out, int out_size, void* d_ws, size_t ws_size,
                              hipStream_t stream) {
  const float* x = (const float*)d_in[0];
  const float* H = (const float*)d_in[1];
  const float* W = (const float*)d_in[2];
  const float* bias = (const float*)d_in[3];
  float* out = (float*)d_out;

  char* ws = (char*)d_ws;
  unsigned short* Hbf = (unsigned short*)ws;                    // [B][N][E] bf16
  unsigned short* HT = Hbf + (size_t)B_ * N_ * E_;              // [B][E][N] bf16
  unsigned short* xsT = HT + (size_t)B_ * N_ * E_;              // [B][C][N] bf16
  float* out2 = (float*)(xsT + (size_t)B_ * C_ * N_);           // [B][E][C] f32
  unsigned short* out2T = (unsigned short*)(out2 + (size_t)B_ * E_ * C_);  // [B][C][E]
  float* Dv = (float*)(out2T + (size_t)B_ * C_ * E_);           // [B][N]
  float* De = Dv + B_ * N_;                                     // [B][E] (contiguous)

  // zero accumulators (harness poisons ws/out with 0xAA each call)
  hipMemsetAsync(Dv, 0, (size_t)(B_ * N_ + B_ * E_) * sizeof(float), stream);
  hipMemsetAsync(out2, 0, (size_t)B_ * E_ * C_ * sizeof(float), stream);
  hipMemsetAsync(d_out, 0, (size_t)out_size * sizeof(float), stream);

  k1_prep<<<dim3(N_ / 128, E_ / 1024, B_), 256, 0, stream>>>(H, Hbf, HT, Dv, De);
  scale_transpose<0><<<dim3(N_ / 128, B_), 256, 0, stream>>>(x, Dv, xsT, N_);
  gemm_bt_splitk<<<dim3(E_ / 128, 4, B_), 256, 0, stream>>>(HT, xsT, out2, E_, N_, N_ / 4);
  scale_transpose<1><<<dim3(E_ / 128, B_), 256, 0, stream>>>(out2, De, out2T, E_);
  gemm_bt_splitk<<<dim3(N_ / 128, 2, B_), 256, 0, stream>>>(Hbf, out2T, out, N_, E_, E_ / 2);
  k5_linear<<<dim3(B_ * N_ / 128), 256, 0, stream>>>(out, W, bias, Dv);
}

// Round 2
// 592.515 us; speedup vs baseline: 1.0067x; 1.0067x over previous
//
#include <hip/hip_runtime.h>

// BatchedHGNNLayer: out = [Dv^-1/2 H De^-1 H^T Dv^-1/2 x] W^T + b
// B=8, N=4096, E=2048, C=128.
// R2 pipeline (no output atomics, split k1 into two streaming passes):
//   memset De (64KB)
//   k1a: H fp32 -> Hbf bf16, Dv row sums (exact, plain stores). 8192 blocks.
//   k1b: Hbf -> HT (LDS transpose) + De col sums (bf16 partials, atomics). 4096 blocks.
//   st0: xsT[c][n] = bf16(x[n][c] * rsqrt(Dv+eps))
//   gemm1 (split-K=2, plain stores): p0,p1 in d_out = HT x xsT   [B][E][C] f32
//   st1_sum: out2T[c][e] = bf16((p0+p1)[e][c] / (De+eps))
//   gemm2 (split-K=2, plain stores): q0 -> d_out, q1 -> HT region (dead)
//   k5: out[n][co] = bf16((q0+q1)[n][ci]*rsqrt(Dv)) @ W^T + b   (in-place on d_out)
// ws: Hbf 128MiB | HT 128MiB (reused for q1) | xsT 8MiB | out2T 4MiB | Dv | De = 268.2MiB

#define EPS 1e-6f
constexpr int B_ = 8, N_ = 4096, E_ = 2048, C_ = 128;

typedef __bf16 bf16x8 __attribute__((ext_vector_type(8)));
typedef float f32x4 __attribute__((ext_vector_type(4)));

__device__ __forceinline__ unsigned int f2bf_pack(float lo, float hi) {
  unsigned int ul = __float_as_uint(lo), uh = __float_as_uint(hi);
  ul = (ul + 0x7fffu + ((ul >> 16) & 1u)) >> 16;
  uh = (uh + 0x7fffu + ((uh >> 16) & 1u)) & 0xffff0000u;
  return uh | ul;
}

__device__ __forceinline__ void gl2lds16(const void* g, void* l) {
  __builtin_amdgcn_global_load_lds(
      (const __attribute__((address_space(1))) void*)g,
      (__attribute__((address_space(3))) void*)l, 16, 0, 0);
}

// ---------------------------------------------------------------------------
// K1a: stream H fp32 -> Hbf bf16 + exact Dv row sums. One wave per row.
// grid B*N/4 = 8192, 256 threads (4 waves).
__global__ __launch_bounds__(256) void k1a_cast_dv(
    const float* __restrict__ H, unsigned short* __restrict__ Hbf,
    float* __restrict__ Dv) {
  const int t = threadIdx.x;
  const int w = t >> 6, l = t & 63;
  const size_t row = (size_t)blockIdx.x * 4 + w;  // over B_*N_
  const float* src = H + row * E_;
  unsigned short* dst = Hbf + row * E_;
  float s = 0.f;
#pragma unroll
  for (int i = 0; i < 8; ++i) {
    const f32x4 v = *(const f32x4*)(src + 256 * i + 4 * l);
    s += v[0] + v[1] + v[2] + v[3];
    uint2 p;
    p.x = f2bf_pack(v[0], v[1]);
    p.y = f2bf_pack(v[2], v[3]);
    *(uint2*)(dst + 256 * i + 4 * l) = p;
  }
#pragma unroll
  for (int o = 32; o; o >>= 1) s += __shfl_xor(s, o);
  if (l == 0) Dv[row] = s;
}

// ---------------------------------------------------------------------------
// K1b: transpose Hbf[n][e] -> HT[e][n] (bf16) via LDS + De column-sum partials.
// grid (N/128, E/128, B) = 4096, 256 threads. Tile 128n x 128e.
__global__ __launch_bounds__(256) void k1b_transpose_de(
    const unsigned short* __restrict__ Hbf, unsigned short* __restrict__ HT,
    float* __restrict__ De) {
  __shared__ unsigned int T[128][66];  // [e][n-pair]
  const int t = threadIdx.x;
  const int b = blockIdx.z;
  const int n0 = blockIdx.x * 128, e0 = blockIdx.y * 128;
  const int q = t >> 2, cq = t & 3;  // rows 2q,2q+1 ; e-chunks of 4
  const unsigned short* r0p = Hbf + ((size_t)b * N_ + n0 + 2 * q) * E_ + e0;
  const unsigned short* r1p = r0p + E_;
#pragma unroll
  for (int i = 0; i < 8; ++i) {
    const int c = 16 * i + 4 * cq;
    const uint2 a = *(const uint2*)(r0p + c);
    const uint2 bb = *(const uint2*)(r1p + c);
    T[c + 0][q] = (a.x & 0xffffu) | (bb.x << 16);
    T[c + 1][q] = (a.x >> 16) | (bb.x & 0xffff0000u);
    T[c + 2][q] = (a.y & 0xffffu) | (bb.y << 16);
    T[c + 3][q] = (a.y >> 16) | (bb.y & 0xffff0000u);
  }
  __syncthreads();
  const int crow = t >> 1, h = t & 1;
  unsigned int u[32];
  float s = 0.f;
#pragma unroll
  for (int i = 0; i < 32; ++i) {
    u[i] = T[crow][h * 32 + i];
    s += __uint_as_float(u[i] << 16) + __uint_as_float(u[i] & 0xffff0000u);
  }
  uint4* dst = (uint4*)(HT + ((size_t)b * E_ + e0 + crow) * N_ + n0 + 64 * h);
#pragma unroll
  for (int i = 0; i < 8; ++i)
    dst[i] = make_uint4(u[4 * i], u[4 * i + 1], u[4 * i + 2], u[4 * i + 3]);
  s += __shfl_xor(s, 1);
  if (h == 0) atomicAdd(&De[b * E_ + e0 + crow], s);
}

// ---------------------------------------------------------------------------
// st0: xsT[c][n] = bf16(x[n][c] * rsqrt(Dv+eps)). grid (N/128, B).
__global__ __launch_bounds__(256) void st0_scale_transpose(
    const float* __restrict__ in, const float* __restrict__ deg,
    unsigned short* __restrict__ outT) {
  __shared__ unsigned int T[128][66];
  const int t = threadIdx.x;
  in += (size_t)blockIdx.y * N_ * 128;
  outT += (size_t)blockIdx.y * 128 * N_;
  deg += (size_t)blockIdx.y * N_;
  const int r0 = blockIdx.x * 128;
  const int q = t >> 2, cq = t & 3;
  const float* row0 = in + (size_t)(r0 + 2 * q) * 128;
  const float* row1 = row0 + 128;
  const float s0 = 1.f / sqrtf(deg[r0 + 2 * q] + EPS);
  const float s1 = 1.f / sqrtf(deg[r0 + 2 * q + 1] + EPS);
#pragma unroll
  for (int i = 0; i < 8; ++i) {
    const int c = 16 * i + 4 * cq;
    const f32x4 a = *(const f32x4*)(row0 + c);
    const f32x4 b2 = *(const f32x4*)(row1 + c);
#pragma unroll
    for (int j = 0; j < 4; ++j) T[c + j][q] = f2bf_pack(a[j] * s0, b2[j] * s1);
  }
  __syncthreads();
  const int crow = t >> 1, h = t & 1;
  unsigned int u[32];
#pragma unroll
  for (int i = 0; i < 32; ++i) u[i] = T[crow][h * 32 + i];
  uint4* dst = (uint4*)(outT + (size_t)crow * N_ + r0 + 64 * h);
#pragma unroll
  for (int i = 0; i < 8; ++i)
    dst[i] = make_uint4(u[4 * i], u[4 * i + 1], u[4 * i + 2], u[4 * i + 3]);
}

// ---------------------------------------------------------------------------
// st1_sum: out2T[c][e] = bf16((p0+p1)[e][c] / (De+eps)). grid (E/128, B).
__global__ __launch_bounds__(256) void st1_sum(
    const float* __restrict__ p0, const float* __restrict__ p1,
    const float* __restrict__ De, unsigned short* __restrict__ out2T) {
  __shared__ unsigned int T[128][66];
  const int t = threadIdx.x;
  const int b = blockIdx.y;
  const int r0 = blockIdx.x * 128;
  const int q = t >> 2, cq = t & 3;
  const size_t base = ((size_t)b * E_ + r0 + 2 * q) * C_;
  const float s0 = 1.f / (De[b * E_ + r0 + 2 * q] + EPS);
  const float s1 = 1.f / (De[b * E_ + r0 + 2 * q + 1] + EPS);
#pragma unroll
  for (int i = 0; i < 8; ++i) {
    const int c = 16 * i + 4 * cq;
    const f32x4 a = *(const f32x4*)(p0 + base + c);
    const f32x4 a1 = *(const f32x4*)(p1 + base + c);
    const f32x4 bb = *(const f32x4*)(p0 + base + C_ + c);
    const f32x4 b1 = *(const f32x4*)(p1 + base + C_ + c);
#pragma unroll
    for (int j = 0; j < 4; ++j)
      T[c + j][q] = f2bf_pack((a[j] + a1[j]) * s0, (bb[j] + b1[j]) * s1);
  }
  __syncthreads();
  const int crow = t >> 1, h = t & 1;
  unsigned int u[32];
#pragma unroll
  for (int i = 0; i < 32; ++i) u[i] = T[crow][h * 32 + i];
  uint4* dst = (uint4*)(out2T + ((size_t)b * C_ + crow) * E_ + r0 + 64 * h);
#pragma unroll
  for (int i = 0; i < 8; ++i)
    dst[i] = make_uint4(u[4 * i], u[4 * i + 1], u[4 * i + 2], u[4 * i + 3]);
}

// ---------------------------------------------------------------------------
// m97-style bf16 gemm_bt, split-K=2, plain stores to partial buffers C0/C1.
// A: [batch][M][Kfull] k-fast bf16; Bt: [batch][128][Kfull] k-fast bf16.
// grid (M/128, 2, batch), 256 threads.
__global__ __launch_bounds__(256) void gemm_bt_splitk(
    const unsigned short* __restrict__ A, const unsigned short* __restrict__ Bt,
    float* __restrict__ C0, float* __restrict__ C1, int M, int Kfull, int Kper) {
  __shared__ unsigned short Als[128 * 32];
  __shared__ unsigned short Bls[128 * 32];
  const int t = threadIdx.x;
  const int w = t >> 6, l = t & 63;
  const int mt = blockIdx.x, sk = blockIdx.y, b = blockIdx.z;
  const unsigned short* Ab = A + ((size_t)b * M + mt * 128) * Kfull + (size_t)sk * Kper;
  const unsigned short* Btb = Bt + (size_t)b * 128 * Kfull + (size_t)sk * Kper;
  const int srow = l >> 2, scol = (l & 3) * 8;
  const unsigned short* ga0 = Ab + (size_t)(w * 32 + srow) * Kfull + scol;
  const unsigned short* ga1 = ga0 + (size_t)16 * Kfull;
  const unsigned short* gb0 = Btb + (size_t)(w * 32 + srow) * Kfull + scol;
  const unsigned short* gb1 = gb0 + (size_t)16 * Kfull;
  unsigned short* const la0 = Als + (w * 32) * 32;
  unsigned short* const la1 = Als + (w * 32 + 16) * 32;
  unsigned short* const lb0 = Bls + (w * 32) * 32;
  unsigned short* const lb1 = Bls + (w * 32 + 16) * 32;
  const int mrow = (w & 1) * 64, ncol = (w >> 1) * 64;
  const int fr = l & 15, fq = l >> 4;
  f32x4 acc[4][4];
#pragma unroll
  for (int i = 0; i < 4; ++i)
#pragma unroll
    for (int j = 0; j < 4; ++j) acc[i][j] = (f32x4){0.f, 0.f, 0.f, 0.f};
  const int nsteps = Kper / 32;
  for (int kt = 0; kt < nsteps; ++kt) {
    __syncthreads();
    gl2lds16(ga0, la0);
    gl2lds16(ga1, la1);
    gl2lds16(gb0, lb0);
    gl2lds16(gb1, lb1);
    ga0 += 32; ga1 += 32; gb0 += 32; gb1 += 32;
    __syncthreads();
    bf16x8 af[4], bfr[4];
#pragma unroll
    for (int i = 0; i < 4; ++i) {
      af[i] = *(const bf16x8*)(Als + (mrow + i * 16 + fr) * 32 + fq * 8);
      bfr[i] = *(const bf16x8*)(Bls + (ncol + i * 16 + fr) * 32 + fq * 8);
    }
#pragma unroll
    for (int i = 0; i < 4; ++i)
#pragma unroll
      for (int j = 0; j < 4; ++j)
        acc[i][j] = __builtin_amdgcn_mfma_f32_16x16x32_bf16(af[i], bfr[j], acc[i][j], 0, 0, 0);
  }
  float* Cb = (sk == 0 ? C0 : C1) + ((size_t)b * M + mt * 128) * 128;
#pragma unroll
  for (int i = 0; i < 4; ++i)
#pragma unroll
    for (int j = 0; j < 4; ++j)
#pragma unroll
      for (int r = 0; r < 4; ++r) {
        const int row = mrow + i * 16 + fq * 4 + r;  // C/D: col=lane&15, row=quad*4+reg
        const int col = ncol + j * 16 + fr;
        Cb[(size_t)row * 128 + col] = acc[i][j][r];
      }
}

// ---------------------------------------------------------------------------
// K5: out = bf16((q0+q1)*rsqrt(Dv)) @ W^T + b, in-place on q0(=d_out).
// grid (B*N/128), 256 threads.
__global__ __launch_bounds__(256) void k5_linear(
    float* __restrict__ io, const float* __restrict__ q1,
    const float* __restrict__ W, const float* __restrict__ bias,
    const float* __restrict__ Dv) {
  __shared__ unsigned short Als[128 * 136];
  __shared__ unsigned short Wls[128 * 136];
  const int t = threadIdx.x;
  const size_t r0 = (size_t)blockIdx.x * 128;
  {
    const int row = t >> 1, h = t & 1;
    const float* src0 = io + (r0 + row) * 128 + h * 64;
    const float* src1 = q1 + (r0 + row) * 128 + h * 64;
    const float sc = 1.f / sqrtf(Dv[r0 + row] + EPS);
    unsigned short* ld = Als + row * 136 + h * 64;
    const float* wsrc = W + row * 128 + h * 64;
    unsigned short* lw = Wls + row * 136 + h * 64;
#pragma unroll
    for (int i = 0; i < 16; ++i) {
      const f32x4 a = *(const f32x4*)(src0 + 4 * i);
      const f32x4 a1 = *(const f32x4*)(src1 + 4 * i);
      uint2 p;
      p.x = f2bf_pack((a[0] + a1[0]) * sc, (a[1] + a1[1]) * sc);
      p.y = f2bf_pack((a[2] + a1[2]) * sc, (a[3] + a1[3]) * sc);
      *(uint2*)(ld + 4 * i) = p;
      const f32x4 ww = *(const f32x4*)(wsrc + 4 * i);
      uint2 pw;
      pw.x = f2bf_pack(ww[0], ww[1]);
      pw.y = f2bf_pack(ww[2], ww[3]);
      *(uint2*)(lw + 4 * i) = pw;
    }
  }
  __syncthreads();
  const int w = t >> 6, l = t & 63;
  const int mrow = (w & 1) * 64, ncol = (w >> 1) * 64;
  const int fr = l & 15, fq = l >> 4;
  f32x4 acc[4][4];
#pragma unroll
  for (int i = 0; i < 4; ++i)
#pragma unroll
    for (int j = 0; j < 4; ++j) acc[i][j] = (f32x4){0.f, 0.f, 0.f, 0.f};
#pragma unroll
  for (int s = 0; s < 4; ++s) {
    bf16x8 af[4], bfr[4];
#pragma unroll
    for (int i = 0; i < 4; ++i) {
      af[i] = *(const bf16x8*)(Als + (mrow + i * 16 + fr) * 136 + s * 32 + fq * 8);
      bfr[i] = *(const bf16x8*)(Wls + (ncol + i * 16 + fr) * 136 + s * 32 + fq * 8);
    }
#pragma unroll
    for (int i = 0; i < 4; ++i)
#pragma unroll
      for (int j = 0; j < 4; ++j)
        acc[i][j] = __builtin_amdgcn_mfma_f32_16x16x32_bf16(af[i], bfr[j], acc[i][j], 0, 0, 0);
  }
#pragma unroll
  for (int i = 0; i < 4; ++i)
#pragma unroll
    for (int j = 0; j < 4; ++j)
#pragma unroll
      for (int r = 0; r < 4; ++r) {
        const int row = mrow + i * 16 + fq * 4 + r;
        const int col = ncol + j * 16 + fr;
        io[(r0 + row) * 128 + col] = acc[i][j][r] + bias[col];
      }
}

// ---------------------------------------------------------------------------
extern "C" void kernel_launch(void* const* d_in, const int* in_sizes, int n_in,
                              void* d_out, int out_size, void* d_ws, size_t ws_size,
                              hipStream_t stream) {
  const float* x = (const float*)d_in[0];
  const float* H = (const float*)d_in[1];
  const float* W = (const float*)d_in[2];
  const float* bias = (const float*)d_in[3];
  float* out = (float*)d_out;

  unsigned short* Hbf = (unsigned short*)d_ws;          // [B][N][E] bf16, 128MiB
  unsigned short* HT = Hbf + (size_t)B_ * N_ * E_;      // [B][E][N] bf16, 128MiB
  unsigned short* xsT = HT + (size_t)B_ * N_ * E_;      // [B][C][N] bf16, 8MiB
  unsigned short* out2T = xsT + (size_t)B_ * C_ * N_;   // [B][C][E] bf16, 4MiB
  float* Dv = (float*)(out2T + (size_t)B_ * C_ * E_);   // [B][N]
  float* De = Dv + B_ * N_;                             // [B][E]

  // gemm1 split partials live in d_out (dead until gemm2); gemm2's second
  // partial lives in the HT region (dead after gemm1).
  float* g1p0 = out;
  float* g1p1 = out + (size_t)B_ * E_ * C_;
  float* g2p1 = (float*)HT;

  hipMemsetAsync(De, 0, (size_t)B_ * E_ * sizeof(float), stream);

  k1a_cast_dv<<<dim3(B_ * N_ / 4), 256, 0, stream>>>(H, Hbf, Dv);
  k1b_transpose_de<<<dim3(N_ / 128, E_ / 128, B_), 256, 0, stream>>>(Hbf, HT, De);
  st0_scale_transpose<<<dim3(N_ / 128, B_), 256, 0, stream>>>(x, Dv, xsT);
  gemm_bt_splitk<<<dim3(E_ / 128, 2, B_), 256, 0, stream>>>(HT, xsT, g1p0, g1p1, E_, N_, N_ / 2);
  st1_sum<<<dim3(E_ / 128, B_), 256, 0, stream>>>(g1p0, g1p1, De, out2T);
  gemm_bt_splitk<<<dim3(N_ / 128, 2, B_), 256, 0, stream>>>(Hbf, out2T, out, g2p1, N_, E_, E_ / 2);
  k5_linear<<<dim3(B_ * N_ / 128), 256, 0, stream>>>(out, g2p1, W, bias, Dv);
}

// Round 3
// 557.595 us; speedup vs baseline: 1.0697x; 1.0626x over previous
//
#include <hip/hip_runtime.h>

// BatchedHGNNLayer: out = [Dv^-1/2 H De^-1 H^T Dv^-1/2 x] W^T + b
// B=8, N=4096, E=2048, C=128.
// R3: kill HT (in-GEMM LDS transpose), fuse De into k1, split-K=4 everywhere.
//   memset De (64KB)
//   k1_fused: H fp32 -> Hbf bf16 + Dv (exact) + De (LDS reduce + atomics). 402 MB.
//   st0: xsT[c][n] = bf16(x[n][c] * rsqrt(Dv+eps))
//   gemm1_tr: P_s[c][e] = sum_n xsT[c][n]*Hbf[n][e]  (B transposed in LDS, splitK=4)
//   st1_sum4: out2T[c][e] = bf16(sum_s P_s / (De+eps))   (pure streaming)
//   gemm2 (splitK=4): Q_s[n][c] = sum_e Hbf[n][e]*out2T[c][e]; Q0=d_out
//   k5: out[n][co] = bf16(sum_s Q_s *rsqrt(Dv)) @ W^T + b  (in-place on d_out)
// ws: Hbf 128MiB | xsT 8MiB | out2T 4MiB | P 32MiB | Q123 48MiB | Dv | De ~= 220MiB

#define EPS 1e-6f
constexpr int B_ = 8, N_ = 4096, E_ = 2048, C_ = 128;

typedef __bf16 bf16x8 __attribute__((ext_vector_type(8)));
typedef float f32x4 __attribute__((ext_vector_type(4)));

__device__ __forceinline__ unsigned int f2bf_pack(float lo, float hi) {
  unsigned int ul = __float_as_uint(lo), uh = __float_as_uint(hi);
  ul = (ul + 0x7fffu + ((ul >> 16) & 1u)) >> 16;
  uh = (uh + 0x7fffu + ((uh >> 16) & 1u)) & 0xffff0000u;
  return uh | ul;
}

__device__ __forceinline__ void gl2lds16(const void* g, void* l) {
  __builtin_amdgcn_global_load_lds(
      (const __attribute__((address_space(1))) void*)g,
      (__attribute__((address_space(3))) void*)l, 16, 0, 0);
}

// ---------------------------------------------------------------------------
// K1: stream H fp32 -> Hbf bf16, Dv row sums (plain stores), De col sums
// (register partials -> LDS cross-wave -> global atomics).
// grid B*N/64 = 512 blocks, 256 threads; wave w handles rows w*16..w*16+15.
__global__ __launch_bounds__(256) void k1_fused(
    const float* __restrict__ H, unsigned short* __restrict__ Hbf,
    float* __restrict__ Dv, float* __restrict__ De) {
  __shared__ float Lde[4][2048];
  const int t = threadIdx.x;
  const int w = t >> 6, l = t & 63;
  const size_t row0 = (size_t)blockIdx.x * 64;
  const int b = (int)(row0 >> 12);  // N_ = 4096
  f32x4 dc[8];
#pragma unroll
  for (int j = 0; j < 8; ++j) dc[j] = (f32x4){0.f, 0.f, 0.f, 0.f};
  for (int i = 0; i < 16; ++i) {
    const size_t r = row0 + w * 16 + i;
    const float* src = H + r * E_;
    unsigned short* dst = Hbf + r * E_;
    float rs = 0.f;
#pragma unroll
    for (int j = 0; j < 8; ++j) {
      const f32x4 v = *(const f32x4*)(src + 256 * j + 4 * l);
      dc[j] += v;
      rs += v[0] + v[1] + v[2] + v[3];
      uint2 p;
      p.x = f2bf_pack(v[0], v[1]);
      p.y = f2bf_pack(v[2], v[3]);
      *(uint2*)(dst + 256 * j + 4 * l) = p;
    }
#pragma unroll
    for (int o = 32; o; o >>= 1) rs += __shfl_xor(rs, o);
    if (l == 0) Dv[r] = rs;
  }
#pragma unroll
  for (int j = 0; j < 8; ++j) *(f32x4*)&Lde[w][256 * j + 4 * l] = dc[j];
  __syncthreads();
  const int c0 = t * 8;
  f32x4 s0 = (f32x4){0.f, 0.f, 0.f, 0.f}, s1 = s0;
#pragma unroll
  for (int ww = 0; ww < 4; ++ww) {
    s0 += *(const f32x4*)&Lde[ww][c0];
    s1 += *(const f32x4*)&Lde[ww][c0 + 4];
  }
  float* dp = De + b * E_ + c0;
#pragma unroll
  for (int j = 0; j < 4; ++j) atomicAdd(dp + j, s0[j]);
#pragma unroll
  for (int j = 0; j < 4; ++j) atomicAdd(dp + 4 + j, s1[j]);
}

// ---------------------------------------------------------------------------
// st0: xsT[c][n] = bf16(x[n][c] * rsqrt(Dv+eps)). grid (N/128, B).
__global__ __launch_bounds__(256) void st0_scale_transpose(
    const float* __restrict__ in, const float* __restrict__ deg,
    unsigned short* __restrict__ outT) {
  __shared__ unsigned int T[128][66];
  const int t = threadIdx.x;
  in += (size_t)blockIdx.y * N_ * 128;
  outT += (size_t)blockIdx.y * 128 * N_;
  deg += (size_t)blockIdx.y * N_;
  const int r0 = blockIdx.x * 128;
  const int q = t >> 2, cq = t & 3;
  const float* row0 = in + (size_t)(r0 + 2 * q) * 128;
  const float* row1 = row0 + 128;
  const float s0 = 1.f / sqrtf(deg[r0 + 2 * q] + EPS);
  const float s1 = 1.f / sqrtf(deg[r0 + 2 * q + 1] + EPS);
#pragma unroll
  for (int i = 0; i < 8; ++i) {
    const int c = 16 * i + 4 * cq;
    const f32x4 a = *(const f32x4*)(row0 + c);
    const f32x4 b2 = *(const f32x4*)(row1 + c);
#pragma unroll
    for (int j = 0; j < 4; ++j) T[c + j][q] = f2bf_pack(a[j] * s0, b2[j] * s1);
  }
  __syncthreads();
  const int crow = t >> 1, h = t & 1;
  unsigned int u[32];
#pragma unroll
  for (int i = 0; i < 32; ++i) u[i] = T[crow][h * 32 + i];
  uint4* dst = (uint4*)(outT + (size_t)crow * N_ + r0 + 64 * h);
#pragma unroll
  for (int i = 0; i < 8; ++i)
    dst[i] = make_uint4(u[4 * i], u[4 * i + 1], u[4 * i + 2], u[4 * i + 3]);
}

// ---------------------------------------------------------------------------
// gemm1: P_sk[b][c][e] = sum_{n in split} xsT[c][n] * Hbf[n][e].
// A = xsT (k-fast, gl2lds staging). B = Hbf (k-MAJOR) -> transposed into LDS
// via packed ds_write_b32 with XOR swizzle (keeps frag ds_read_b128 16B-aligned).
// grid (E/128, 4, B), 256 threads.
__global__ __launch_bounds__(256) void gemm1_tr(
    const unsigned short* __restrict__ Hbf, const unsigned short* __restrict__ xsT,
    float* __restrict__ P) {
  __shared__ unsigned short Als[128 * 32];
  __shared__ unsigned short Bls[128 * 40];  // [e][n'], n' = n ^ 8*(q&3) swizzle
  const int t = threadIdx.x;
  const int w = t >> 6, l = t & 63;
  const int et = blockIdx.x, sk = blockIdx.y, b = blockIdx.z;
  const int k0 = sk * (N_ / 4);
  const int e0 = et * 128;
  const unsigned short* Ab = xsT + (size_t)b * C_ * N_ + k0;
  const int srow = l >> 2, scol = (l & 3) * 8;
  const unsigned short* ga0 = Ab + (size_t)(w * 32 + srow) * N_ + scol;
  const unsigned short* ga1 = ga0 + (size_t)16 * N_;
  unsigned short* const la0 = Als + (w * 32) * 32;
  unsigned short* const la1 = Als + (w * 32 + 16) * 32;
  const int np = t >> 4, q = t & 15;
  const int sw = (q & 3) << 3;
  const unsigned short* gb = Hbf + (size_t)b * N_ * E_ + (size_t)(k0 + 2 * np) * E_ + e0 + 8 * q;
  const int mrow = (w & 1) * 64, ncol = (w >> 1) * 64;
  const int fr = l & 15, fq = l >> 4;
  f32x4 acc[4][4];
#pragma unroll
  for (int i = 0; i < 4; ++i)
#pragma unroll
    for (int j = 0; j < 4; ++j) acc[i][j] = (f32x4){0.f, 0.f, 0.f, 0.f};
  uint4 pl = *(const uint4*)gb;
  uint4 ph = *(const uint4*)(gb + E_);
  const int nsteps = (N_ / 4) / 32;  // 32
  for (int kt = 0; kt < nsteps; ++kt) {
    __syncthreads();
    gl2lds16(ga0, la0);
    gl2lds16(ga1, la1);
    ga0 += 32;
    ga1 += 32;
    {
      unsigned int wl[4] = {pl.x, pl.y, pl.z, pl.w};
      unsigned int wh[4] = {ph.x, ph.y, ph.z, ph.w};
#pragma unroll
      for (int j = 0; j < 8; ++j) {
        const unsigned int lo16 = (wl[j >> 1] >> (16 * (j & 1))) & 0xffffu;
        const unsigned int hi16 = (wh[j >> 1] >> (16 * (j & 1))) & 0xffffu;
        *(unsigned int*)(Bls + (8 * q + j) * 40 + ((2 * np) ^ sw)) = lo16 | (hi16 << 16);
      }
    }
    if (kt + 1 < nsteps) {
      const unsigned short* g2 = gb + (size_t)(kt + 1) * 32 * E_;
      pl = *(const uint4*)g2;
      ph = *(const uint4*)(g2 + E_);
    }
    __syncthreads();
    bf16x8 af[4], bfr[4];
#pragma unroll
    for (int i = 0; i < 4; ++i) {
      af[i] = *(const bf16x8*)(Als + (mrow + i * 16 + fr) * 32 + fq * 8);
      const int brow = ncol + i * 16 + fr;
      const int nsw = (fq * 8) ^ (((brow >> 3) & 3) << 3);
      bfr[i] = *(const bf16x8*)(Bls + brow * 40 + nsw);
    }
#pragma unroll
    for (int i = 0; i < 4; ++i)
#pragma unroll
      for (int j = 0; j < 4; ++j)
        acc[i][j] = __builtin_amdgcn_mfma_f32_16x16x32_bf16(af[i], bfr[j], acc[i][j], 0, 0, 0);
  }
  float* Pb = P + (((size_t)sk * B_ + b) * C_) * E_ + e0;
#pragma unroll
  for (int i = 0; i < 4; ++i)
#pragma unroll
    for (int j = 0; j < 4; ++j)
#pragma unroll
      for (int r = 0; r < 4; ++r) {
        const int row = mrow + i * 16 + fq * 4 + r;  // C/D: col=lane&15, row=quad*4+reg
        const int col = ncol + j * 16 + fr;
        Pb[(size_t)row * E_ + col] = acc[i][j][r];
      }
}

// ---------------------------------------------------------------------------
// st1_sum4: out2T[b][c][e] = bf16(sum_s P_s[b][c][e] / (De[b][e]+eps)). Streaming.
__global__ __launch_bounds__(256) void st1_sum4(
    const float* __restrict__ P, const float* __restrict__ De,
    unsigned short* __restrict__ out2T) {
  const size_t SP = (size_t)B_ * C_ * E_;
  const size_t idx = ((size_t)blockIdx.x * 256 + threadIdx.x) * 8;
  const int e = (int)(idx & (E_ - 1));
  const int b = (int)(idx >> 18);  // C_*E_ = 2^18
  f32x4 s0 = (f32x4){0.f, 0.f, 0.f, 0.f}, s1 = s0;
#pragma unroll
  for (int s = 0; s < 4; ++s) {
    s0 += *(const f32x4*)(P + s * SP + idx);
    s1 += *(const f32x4*)(P + s * SP + idx + 4);
  }
  const f32x4 d0 = *(const f32x4*)(De + b * E_ + e);
  const f32x4 d1 = *(const f32x4*)(De + b * E_ + e + 4);
  uint4 o;
  o.x = f2bf_pack(s0[0] / (d0[0] + EPS), s0[1] / (d0[1] + EPS));
  o.y = f2bf_pack(s0[2] / (d0[2] + EPS), s0[3] / (d0[3] + EPS));
  o.z = f2bf_pack(s1[0] / (d1[0] + EPS), s1[1] / (d1[1] + EPS));
  o.w = f2bf_pack(s1[2] / (d1[2] + EPS), s1[3] / (d1[3] + EPS));
  *(uint4*)(out2T + idx) = o;
}

// ---------------------------------------------------------------------------
// gemm2: Q_sk[b][n][c] = sum_{e in split} Hbf[n][e] * out2T[c][e]. Both k-fast.
// grid (N/128, 4, B), 256 threads. m97-style, plain stores to Q0..Q3.
__global__ __launch_bounds__(256) void gemm_bt_splitk4(
    const unsigned short* __restrict__ A, const unsigned short* __restrict__ Bt,
    float* __restrict__ Q0, float* __restrict__ Q1, float* __restrict__ Q2,
    float* __restrict__ Q3, int M, int Kfull, int Kper) {
  __shared__ unsigned short Als[128 * 32];
  __shared__ unsigned short Bls[128 * 32];
  const int t = threadIdx.x;
  const int w = t >> 6, l = t & 63;
  const int mt = blockIdx.x, sk = blockIdx.y, b = blockIdx.z;
  const unsigned short* Ab = A + ((size_t)b * M + mt * 128) * Kfull + (size_t)sk * Kper;
  const unsigned short* Btb = Bt + (size_t)b * 128 * Kfull + (size_t)sk * Kper;
  const int srow = l >> 2, scol = (l & 3) * 8;
  const unsigned short* ga0 = Ab + (size_t)(w * 32 + srow) * Kfull + scol;
  const unsigned short* ga1 = ga0 + (size_t)16 * Kfull;
  const unsigned short* gb0 = Btb + (size_t)(w * 32 + srow) * Kfull + scol;
  const unsigned short* gb1 = gb0 + (size_t)16 * Kfull;
  unsigned short* const la0 = Als + (w * 32) * 32;
  unsigned short* const la1 = Als + (w * 32 + 16) * 32;
  unsigned short* const lb0 = Bls + (w * 32) * 32;
  unsigned short* const lb1 = Bls + (w * 32 + 16) * 32;
  const int mrow = (w & 1) * 64, ncol = (w >> 1) * 64;
  const int fr = l & 15, fq = l >> 4;
  f32x4 acc[4][4];
#pragma unroll
  for (int i = 0; i < 4; ++i)
#pragma unroll
    for (int j = 0; j < 4; ++j) acc[i][j] = (f32x4){0.f, 0.f, 0.f, 0.f};
  const int nsteps = Kper / 32;
  for (int kt = 0; kt < nsteps; ++kt) {
    __syncthreads();
    gl2lds16(ga0, la0);
    gl2lds16(ga1, la1);
    gl2lds16(gb0, lb0);
    gl2lds16(gb1, lb1);
    ga0 += 32; ga1 += 32; gb0 += 32; gb1 += 32;
    __syncthreads();
    bf16x8 af[4], bfr[4];
#pragma unroll
    for (int i = 0; i < 4; ++i) {
      af[i] = *(const bf16x8*)(Als + (mrow + i * 16 + fr) * 32 + fq * 8);
      bfr[i] = *(const bf16x8*)(Bls + (ncol + i * 16 + fr) * 32 + fq * 8);
    }
#pragma unroll
    for (int i = 0; i < 4; ++i)
#pragma unroll
      for (int j = 0; j < 4; ++j)
        acc[i][j] = __builtin_amdgcn_mfma_f32_16x16x32_bf16(af[i], bfr[j], acc[i][j], 0, 0, 0);
  }
  float* Q = (sk == 0) ? Q0 : (sk == 1) ? Q1 : (sk == 2) ? Q2 : Q3;
  float* Cb = Q + ((size_t)b * M + mt * 128) * 128;
#pragma unroll
  for (int i = 0; i < 4; ++i)
#pragma unroll
    for (int j = 0; j < 4; ++j)
#pragma unroll
      for (int r = 0; r < 4; ++r) {
        const int row = mrow + i * 16 + fq * 4 + r;
        const int col = ncol + j * 16 + fr;
        Cb[(size_t)row * 128 + col] = acc[i][j][r];
      }
}

// ---------------------------------------------------------------------------
// K5: out = bf16(sum_s Q_s * rsqrt(Dv)) @ W^T + b, in-place on Q0(=d_out).
__global__ __launch_bounds__(256) void k5_linear4(
    float* __restrict__ io, const float* __restrict__ q1,
    const float* __restrict__ q2, const float* __restrict__ q3,
    const float* __restrict__ W, const float* __restrict__ bias,
    const float* __restrict__ Dv) {
  __shared__ unsigned short Als[128 * 136];
  __shared__ unsigned short Wls[128 * 136];
  const int t = threadIdx.x;
  const size_t r0 = (size_t)blockIdx.x * 128;
  {
    const int row = t >> 1, h = t & 1;
    const size_t off = (r0 + row) * 128 + h * 64;
    const float sc = 1.f / sqrtf(Dv[r0 + row] + EPS);
    unsigned short* ld = Als + row * 136 + h * 64;
    const float* wsrc = W + row * 128 + h * 64;
    unsigned short* lw = Wls + row * 136 + h * 64;
#pragma unroll
    for (int i = 0; i < 16; ++i) {
      f32x4 a = *(const f32x4*)(io + off + 4 * i);
      a += *(const f32x4*)(q1 + off + 4 * i);
      a += *(const f32x4*)(q2 + off + 4 * i);
      a += *(const f32x4*)(q3 + off + 4 * i);
      uint2 p;
      p.x = f2bf_pack(a[0] * sc, a[1] * sc);
      p.y = f2bf_pack(a[2] * sc, a[3] * sc);
      *(uint2*)(ld + 4 * i) = p;
      const f32x4 ww = *(const f32x4*)(wsrc + 4 * i);
      uint2 pw;
      pw.x = f2bf_pack(ww[0], ww[1]);
      pw.y = f2bf_pack(ww[2], ww[3]);
      *(uint2*)(lw + 4 * i) = pw;
    }
  }
  __syncthreads();
  const int w = t >> 6, l = t & 63;
  const int mrow = (w & 1) * 64, ncol = (w >> 1) * 64;
  const int fr = l & 15, fq = l >> 4;
  f32x4 acc[4][4];
#pragma unroll
  for (int i = 0; i < 4; ++i)
#pragma unroll
    for (int j = 0; j < 4; ++j) acc[i][j] = (f32x4){0.f, 0.f, 0.f, 0.f};
#pragma unroll
  for (int s = 0; s < 4; ++s) {
    bf16x8 af[4], bfr[4];
#pragma unroll
    for (int i = 0; i < 4; ++i) {
      af[i] = *(const bf16x8*)(Als + (mrow + i * 16 + fr) * 136 + s * 32 + fq * 8);
      bfr[i] = *(const bf16x8*)(Wls + (ncol + i * 16 + fr) * 136 + s * 32 + fq * 8);
    }
#pragma unroll
    for (int i = 0; i < 4; ++i)
#pragma unroll
      for (int j = 0; j < 4; ++j)
        acc[i][j] = __builtin_amdgcn_mfma_f32_16x16x32_bf16(af[i], bfr[j], acc[i][j], 0, 0, 0);
  }
#pragma unroll
  for (int i = 0; i < 4; ++i)
#pragma unroll
    for (int j = 0; j < 4; ++j)
#pragma unroll
      for (int r = 0; r < 4; ++r) {
        const int row = mrow + i * 16 + fq * 4 + r;
        const int col = ncol + j * 16 + fr;
        io[(r0 + row) * 128 + col] = acc[i][j][r] + bias[col];
      }
}

// ---------------------------------------------------------------------------
extern "C" void kernel_launch(void* const* d_in, const int* in_sizes, int n_in,
                              void* d_out, int out_size, void* d_ws, size_t ws_size,
                              hipStream_t stream) {
  const float* x = (const float*)d_in[0];
  const float* H = (const float*)d_in[1];
  const float* W = (const float*)d_in[2];
  const float* bias = (const float*)d_in[3];
  float* out = (float*)d_out;

  unsigned short* Hbf = (unsigned short*)d_ws;          // [B][N][E] bf16, 128MiB
  unsigned short* xsT = Hbf + (size_t)B_ * N_ * E_;     // [B][C][N] bf16, 8MiB
  unsigned short* out2T = xsT + (size_t)B_ * C_ * N_;   // [B][C][E] bf16, 4MiB
  float* P = (float*)(out2T + (size_t)B_ * C_ * E_);    // [4][B][C][E] f32, 32MiB
  float* Q123 = P + 4 * (size_t)B_ * C_ * E_;           // [3][B][N][C] f32, 48MiB
  float* Dv = Q123 + 3 * (size_t)B_ * N_ * C_;          // [B][N]
  float* De = Dv + B_ * N_;                             // [B][E]

  float* q1 = Q123;
  float* q2 = Q123 + (size_t)B_ * N_ * C_;
  float* q3 = Q123 + 2 * (size_t)B_ * N_ * C_;

  hipMemsetAsync(De, 0, (size_t)B_ * E_ * sizeof(float), stream);

  k1_fused<<<dim3(B_ * N_ / 64), 256, 0, stream>>>(H, Hbf, Dv, De);
  st0_scale_transpose<<<dim3(N_ / 128, B_), 256, 0, stream>>>(x, Dv, xsT);
  gemm1_tr<<<dim3(E_ / 128, 4, B_), 256, 0, stream>>>(Hbf, xsT, P);
  st1_sum4<<<dim3(B_ * C_ * E_ / 8 / 256), 256, 0, stream>>>(P, De, out2T);
  gemm_bt_splitk4<<<dim3(N_ / 128, 4, B_), 256, 0, stream>>>(
      Hbf, out2T, out, q1, q2, q3, N_, E_, E_ / 4);
  k5_linear4<<<dim3(B_ * N_ / 128), 256, 0, stream>>>(out, q1, q2, q3, W, bias, Dv);
}